// Round 17
// baseline (185.003 us; speedup 1.0000x reference)
//
#include <hip/hip_runtime.h>
#include <hip/hip_bf16.h>
#include <hip/hip_fp16.h>

typedef _Float16 f16;
typedef f16 f16x8 __attribute__((ext_vector_type(8)));
typedef f16 f16x4 __attribute__((ext_vector_type(4)));
typedef f16 f16x2 __attribute__((ext_vector_type(2)));
typedef float f32x4 __attribute__((ext_vector_type(4)));
typedef float f32x16 __attribute__((ext_vector_type(16)));
typedef unsigned int u32x4 __attribute__((ext_vector_type(4)));
typedef unsigned int u32x2 __attribute__((ext_vector_type(2)));

#define MFMA16(a, b, c) __builtin_amdgcn_mfma_f32_16x16x32_f16(a, b, c, 0, 0, 0)
#define MFMA32(a, b, c) __builtin_amdgcn_mfma_f32_32x32x16_f16(a, b, c, 0, 0, 0)

constexpr int BB = 4, SS = 2048, DD = 1024, HH = 16, HDIM = 64;
constexpr int MM = BB * SS; // 8192
constexpr float QSCALE = 0.125f * 1.44269504088896340736f;

// K/V CHUNK-TILED: 16B chunk (bh, tile, slot, row) at f16 offset
//   (((bh*32 + tile)*8 + slot)*64 + row) * 8
__device__ __forceinline__ void gl_lds16(const void* g, void* l) {
  __builtin_amdgcn_global_load_lds((const __attribute__((address_space(1))) void*)g,
                                   (__attribute__((address_space(3))) void*)l, 16, 0, 0);
}

// ---------------- fp32 -> f16 conversion (x + 4 weights, one launch) ----------------
__global__ __launch_bounds__(256) void cvt_all_kernel(const float* __restrict__ x,
                                                      const float* __restrict__ w0,
                                                      const float* __restrict__ w1,
                                                      const float* __restrict__ w2,
                                                      const float* __restrict__ w3,
                                                      f16* xh, f16* o0, f16* o1,
                                                      f16* o2, f16* o3) {
  int bid = blockIdx.x;
  const float* in; f16* out; int idx;
  if (bid < MM * DD / 4 / 256) {
    in = x; out = xh; idx = bid * 256 + threadIdx.x;
  } else {
    int wb = bid - MM * DD / 4 / 256;
    int which = wb >> 10;
    in = which == 0 ? w0 : which == 1 ? w1 : which == 2 ? w2 : w3;
    out = which == 0 ? o0 : which == 1 ? o1 : which == 2 ? o2 : o3;
    idx = (wb & 1023) * 256 + threadIdx.x;
  }
  f32x4 v = reinterpret_cast<const f32x4*>(in)[idx];
  f16x4 o;
  o[0] = (f16)v[0]; o[1] = (f16)v[1]; o[2] = (f16)v[2]; o[3] = (f16)v[3];
  reinterpret_cast<f16x4*>(out)[idx] = o;
}

// ---------------- 8-wave 256x128 pipelined GEMM (proven) ----------------
template <bool QKV>
__global__ __launch_bounds__(512) void gemm8_kernel(const f16* __restrict__ A,
                                                    const f16* __restrict__ W0,
                                                    const f16* __restrict__ W1,
                                                    const f16* __restrict__ W2,
                                                    const float* __restrict__ b0,
                                                    const float* __restrict__ b1,
                                                    const float* __restrict__ b2,
                                                    void* __restrict__ O0,
                                                    void* __restrict__ O1,
                                                    void* __restrict__ O2) {
  constexpr int NT = 16;
  constexpr int BUF = 256 * 64 + 128 * 64;
  __shared__ __align__(16) f16 smem[3 * BUF];

  const int p = blockIdx.x;
  const int bl = p >> 3;
  const int NS = QKV ? 24 : 8;
  const int nn = bl % NS;
  const int my = (p & 7) + 8 * (bl / NS);
  const int mat = QKV ? (nn >> 3) : 0;
  const int m0 = my * 256;
  const int n0 = (nn & 7) * 128;

  const f16* W = mat == 0 ? W0 : (mat == 1 ? W1 : W2);
  const float* bias = mat == 0 ? b0 : (mat == 1 ? b1 : b2);

  const int tid = threadIdx.x;
  const int w = tid >> 6, lane = tid & 63;
  const int wm = w >> 2, wn = w & 3;
  const int g = lane >> 4, r = lane & 15;

  f32x4 acc[8][2] = {};

#define STAGE_A(I, PB, KT)                                                              \
  do {                                                                                  \
    int cid_ = ((I)*8 + w) * 64 + lane;                                                 \
    int row_ = cid_ >> 3, c_ = cid_ & 7;                                                \
    gl_lds16(A + (size_t)(m0 + row_) * 1024 + (KT) + ((c_ ^ (row_ & 7)) << 3),          \
             smem + (PB) + ((I)*8 + w) * 512);                                          \
  } while (0)
#define STAGE_B(I, PB, KT)                                                              \
  do {                                                                                  \
    int cid_ = ((I)*8 + w) * 64 + lane;                                                 \
    int row_ = cid_ >> 3, c_ = cid_ & 7;                                                \
    gl_lds16(W + (size_t)(n0 + row_) * 1024 + (KT) + ((c_ ^ (row_ & 7)) << 3),          \
             smem + (PB) + 256 * 64 + ((I)*8 + w) * 512);                               \
  } while (0)

#pragma unroll
  for (int i = 0; i < 4; ++i) STAGE_A(i, 0, 0);
#pragma unroll
  for (int i = 0; i < 2; ++i) STAGE_B(i, 0, 0);
#pragma unroll
  for (int i = 0; i < 4; ++i) STAGE_A(i, BUF, 64);
#pragma unroll
  for (int i = 0; i < 2; ++i) STAGE_B(i, BUF, 64);
  __builtin_amdgcn_sched_barrier(0);
  asm volatile("s_waitcnt vmcnt(6)" ::: "memory");
  __builtin_amdgcn_s_barrier();
  __builtin_amdgcn_sched_barrier(0);

  for (int t = 0; t < NT; ++t) {
    const f16* Ab = smem + (t % 3) * BUF;
    const f16* Wb = Ab + 256 * 64;
    const int pb = ((t + 2) % 3) * BUF;
    const int kpf = (t + 2) * 64;
    const bool do_pf = (t + 2) < NT;

    f16x8 wf[2][2];
#pragma unroll
    for (int ks = 0; ks < 2; ++ks)
#pragma unroll
      for (int j = 0; j < 2; ++j) {
        int rowW = wn * 32 + j * 16 + r;
        wf[ks][j] = *reinterpret_cast<const f16x8*>(
            Wb + rowW * 64 + (((ks << 2) | g) ^ (rowW & 7)) * 8);
      }

    if (do_pf) { STAGE_A(0, pb, kpf); STAGE_A(1, pb, kpf); STAGE_B(0, pb, kpf); }
    __builtin_amdgcn_s_setprio(1);
#pragma unroll
    for (int ks = 0; ks < 2; ++ks)
#pragma unroll
      for (int i = 0; i < 4; ++i) {
        int rowA = wm * 128 + i * 16 + r;
        f16x8 af = *reinterpret_cast<const f16x8*>(
            Ab + rowA * 64 + (((ks << 2) | g) ^ (rowA & 7)) * 8);
        acc[i][0] = MFMA16(af, wf[ks][0], acc[i][0]);
        acc[i][1] = MFMA16(af, wf[ks][1], acc[i][1]);
      }
    __builtin_amdgcn_s_setprio(0);

    if (do_pf) { STAGE_A(2, pb, kpf); STAGE_A(3, pb, kpf); STAGE_B(1, pb, kpf); }
    __builtin_amdgcn_s_setprio(1);
#pragma unroll
    for (int ks = 0; ks < 2; ++ks)
#pragma unroll
      for (int i = 0; i < 4; ++i) {
        int rowA = wm * 128 + 64 + i * 16 + r;
        f16x8 af = *reinterpret_cast<const f16x8*>(
            Ab + rowA * 64 + (((ks << 2) | g) ^ (rowA & 7)) * 8);
        acc[4 + i][0] = MFMA16(af, wf[ks][0], acc[4 + i][0]);
        acc[4 + i][1] = MFMA16(af, wf[ks][1], acc[4 + i][1]);
      }
    __builtin_amdgcn_s_setprio(0);

    __builtin_amdgcn_sched_barrier(0);
    if (t < NT - 2) {
      asm volatile("s_waitcnt vmcnt(6)" ::: "memory");
      __builtin_amdgcn_s_barrier();
    } else if (t == NT - 2) {
      asm volatile("s_waitcnt vmcnt(0)" ::: "memory");
      __builtin_amdgcn_s_barrier();
    }
    __builtin_amdgcn_sched_barrier(0);
  }
#undef STAGE_A
#undef STAGE_B

  const int sbase = m0 & 2047, bb = m0 >> 11;
  if constexpr (!QKV) {
    float* Out = reinterpret_cast<float*>(O0);
#pragma unroll
    for (int ii = 0; ii < 8; ++ii) {
      int rowoff = (ii >> 2) * 64 + (ii & 3) * 16;
#pragma unroll
      for (int j = 0; j < 2; ++j)
#pragma unroll
        for (int q = 0; q < 4; ++q) {
          int gm = m0 + wm * 128 + rowoff + g * 4 + q;
          int gn = n0 + wn * 32 + j * 16 + r;
          Out[(size_t)gm * 1024 + gn] = acc[ii][j][q] + bias[gn];
        }
    }
  } else if (mat == 0) {
    f16* Qo = reinterpret_cast<f16*>(O0);
#pragma unroll
    for (int ii = 0; ii < 8; ++ii) {
      int rowoff = (ii >> 2) * 64 + (ii & 3) * 16;
#pragma unroll
      for (int j = 0; j < 2; ++j)
#pragma unroll
        for (int q = 0; q < 4; ++q) {
          int gm = m0 + wm * 128 + rowoff + g * 4 + q;
          int gn = n0 + wn * 32 + j * 16 + r;
          float v = (acc[ii][j][q] + bias[gn]) * QSCALE;
          int b = gm >> 11, s = gm & 2047;
          int hh = gn >> 6, hd = gn & 63;
          Qo[(((size_t)(b * HH + hh)) * SS + s) * HDIM + hd] = (f16)v;
        }
    }
  } else if (mat == 1) {
    f16* Ko = reinterpret_cast<f16*>(O1);
    __syncthreads();
    f16* T = smem;
#pragma unroll
    for (int ii = 0; ii < 8; ++ii) {
      int rowoff = (ii >> 2) * 64 + (ii & 3) * 16;
#pragma unroll
      for (int j = 0; j < 2; ++j)
#pragma unroll
        for (int q = 0; q < 4; ++q) {
          int ml = wm * 128 + rowoff + g * 4 + q;
          int nl = wn * 32 + j * 16 + r;
          T[ml * 136 + nl] = (f16)(acc[ii][j][q] + bias[n0 + nl]);
        }
    }
    __syncthreads();
#pragma unroll
    for (int it = 0; it < 8; ++it) {
      int cid = it * 512 + tid;
      int row_s = cid & 255, ns = cid >> 8;
      u32x4 v = *reinterpret_cast<const u32x4*>(T + row_s * 136 + ns * 8);
      int gn0 = n0 + ns * 8;
      int hh = gn0 >> 6, slot = (gn0 & 63) >> 3;
      int tile = (sbase >> 6) + (row_s >> 6), row = row_s & 63;
      size_t off = ((((size_t)(bb * HH + hh) * 32 + tile) * 8 + slot) * 64 + row) * 8;
      *reinterpret_cast<u32x4*>(Ko + off) = v;
    }
  } else {
    f16* Vo = reinterpret_cast<f16*>(O2);
    __syncthreads();
    f16* T = smem;
#pragma unroll
    for (int ii = 0; ii < 8; ++ii) {
      int rowoff = (ii >> 2) * 64 + (ii & 3) * 16;
#pragma unroll
      for (int j = 0; j < 2; ++j)
#pragma unroll
        for (int q = 0; q < 4; ++q) {
          int ml = wm * 128 + rowoff + g * 4 + q;
          int nl = wn * 32 + j * 16 + r;
          T[nl * 264 + ml] = (f16)(acc[ii][j][q] + bias[n0 + nl]);
        }
    }
    __syncthreads();
#pragma unroll
    for (int it = 0; it < 8; ++it) {
      int cid = it * 512 + tid;
      int hd_l = cid & 127, rest = cid >> 7;
      int sl = rest & 7, tl = rest >> 3;
      u32x4 v = *reinterpret_cast<const u32x4*>(T + hd_l * 264 + tl * 64 + sl * 8);
      int gn = n0 + hd_l, hh = gn >> 6, hd = gn & 63;
      int tile = (sbase >> 6) + tl;
      size_t off = ((((size_t)(bb * HH + hh) * 32 + tile) * 8 + sl) * 64 + hd) * 8;
      *reinterpret_cast<u32x4*>(Vo + off) = v;
    }
  }
}

// ---------------- flash attention: 2 tiles/barrier + lsum via ones-MFMA ----------------
// Row-sums computed on the MFMA pipe (B = ones) -> normalization is lane-local:
// no f16 trees, no shuffles, no Lw broadcast.
__global__ __launch_bounds__(256, 2) void attn_kernel(const f16* __restrict__ Q,
                                                      const f16* __restrict__ K,
                                                      const f16* __restrict__ Vt,
                                                      f16* __restrict__ AO) {
  __shared__ __align__(16) f16 Kls[4][8 * 512];
  __shared__ __align__(16) f16 Vls[5][8 * 512];

  const int p = blockIdx.x;
  const int qx = (p >> 3) & 7;
  const int bh = (p & 7) | ((p >> 6) << 3);
  const int q0 = qx * 256;

  const int tid = threadIdx.x;
  const int w = tid >> 6, lane = tid & 63;
  const int q31 = lane & 31;
  const int h = lane >> 5;
  const f16* Kg = K + (size_t)bh * (SS * HDIM);
  const f16* Vg = Vt + (size_t)bh * (SS * HDIM);
  const int s0 = 2 * w;
  const int rofs = h * 512 + q31 * 8;

  const f16* Qg = Q + ((size_t)bh * SS + q0 + w * 64 + q31) * HDIM + 8 * h;
  f16x8 qf[2][4];
#pragma unroll
  for (int f = 0; f < 2; ++f)
#pragma unroll
    for (int m = 0; m < 4; ++m)
      qf[f][m] = *reinterpret_cast<const f16x8*>(Qg + f * 32 * HDIM + 16 * m);

  f32x16 oacc[2][2] = {};
  f32x16 ocsum[2] = {};         // row-sums of P, same reg->q mapping as oacc
  f16x8 onesf;
#pragma unroll
  for (int e = 0; e < 8; ++e) onesf[e] = (f16)1.0f;
  unsigned pkP0[8], pkP1[8];

#define STAGE_T(T1)                                                                      \
  do {                                                                                   \
    f16* kdst = &Kls[(T1) & 3][0];                                                       \
    f16* vdst = &Vls[(T1) % 5][0];                                                       \
    _Pragma("unroll") for (int i = 0; i < 2; ++i) {                                      \
      int s_idx = s0 + i;                                                                \
      gl_lds16(Kg + (size_t)((T1)*512 + s_idx * 64 + lane) * 8, kdst + s_idx * 512);     \
      gl_lds16(Vg + (size_t)((T1)*512 + s_idx * 64 + lane) * 8, vdst + s_idx * 512);     \
    }                                                                                    \
  } while (0)

#define QK_PHASE(KC, KB, SC0, SC1)                                                   \
  do {                                                                               \
    _Pragma("unroll") for (int m = 0; m < 4; ++m) {                                  \
      f16x8 kf = *reinterpret_cast<const f16x8*>((KC) + m * 1024 + (KB)*256 + rofs); \
      SC0 = MFMA32(kf, qf[0][m], SC0);                                               \
      SC1 = MFMA32(kf, qf[1][m], SC1);                                               \
    }                                                                                \
  } while (0)

#define PV_PHASE(VPTR, JB)                                                               \
  do {                                                                                   \
    _Pragma("unroll") for (int jl = 0; jl < 2; ++jl) {                                   \
      auto a0 = __builtin_amdgcn_permlane32_swap(pkP0[4 * jl + 0], pkP0[4 * jl + 2],     \
                                                 false, false);                          \
      auto a1 = __builtin_amdgcn_permlane32_swap(pkP0[4 * jl + 1], pkP0[4 * jl + 3],     \
                                                 false, false);                          \
      u32x4 fa = {(unsigned)a0[0], (unsigned)a1[0], (unsigned)a0[1], (unsigned)a1[1]};   \
      f16x8 pa0 = __builtin_bit_cast(f16x8, fa);                                         \
      auto b0 = __builtin_amdgcn_permlane32_swap(pkP1[4 * jl + 0], pkP1[4 * jl + 2],     \
                                                 false, false);                          \
      auto b1 = __builtin_amdgcn_permlane32_swap(pkP1[4 * jl + 1], pkP1[4 * jl + 3],     \
                                                 false, false);                          \
      u32x4 fb = {(unsigned)b0[0], (unsigned)b1[0], (unsigned)b0[1], (unsigned)b1[1]};   \
      f16x8 pa1 = __builtin_bit_cast(f16x8, fb);                                         \
      const int j = (JB) + jl;                                                           \
      _Pragma("unroll") for (int vb = 0; vb < 2; ++vb) {                                 \
        f16x8 vbf = *reinterpret_cast<const f16x8*>((VPTR) + j * 1024 + vb * 256 + rofs);\
        oacc[0][vb] = MFMA32(pa0, vbf, oacc[0][vb]);                                     \
        oacc[1][vb] = MFMA32(pa1, vbf, oacc[1][vb]);                                     \
      }                                                                                  \
      ocsum[0] = MFMA32(pa0, onesf, ocsum[0]);                                           \
      ocsum[1] = MFMA32(pa1, onesf, ocsum[1]);                                           \
    }                                                                                    \
  } while (0)

#define SM_PHASE(SC0, SC1)                                                               \
  do {                                                                                   \
    _Pragma("unroll") for (int rp = 0; rp < 4; ++rp)                                     \
        _Pragma("unroll") for (int pp = 0; pp < 2; ++pp) {                               \
      float a0 = __builtin_amdgcn_exp2f((SC0)[4 * rp + 2 * pp]);                         \
      float a1 = __builtin_amdgcn_exp2f((SC0)[4 * rp + 2 * pp + 1]);                     \
      pkP0[2 * rp + pp] = __builtin_bit_cast(unsigned, __builtin_amdgcn_cvt_pkrtz(a0, a1));\
      float b0 = __builtin_amdgcn_exp2f((SC1)[4 * rp + 2 * pp]);                         \
      float b1 = __builtin_amdgcn_exp2f((SC1)[4 * rp + 2 * pp + 1]);                     \
      pkP1[2 * rp + pp] = __builtin_bit_cast(unsigned, __builtin_amdgcn_cvt_pkrtz(b0, b1));\
    }                                                                                    \
  } while (0)

#define TILE_BODY(T)                                                                     \
  do {                                                                                   \
    const f16* Kc = &Kls[(T) & 3][0];                                                    \
    const f16* Vcur = &Vls[(T) % 5][0];                                                  \
    const f16* Vprev = &Vls[((T) + 4) % 5][0];                                           \
    {                                                                                    \
      f32x16 sc0 = {}, sc1 = {};                                                         \
      __builtin_amdgcn_s_setprio(1);                                                     \
      QK_PHASE(Kc, 0, sc0, sc1);                                                         \
      if ((T) > 0) PV_PHASE(Vprev, 2);                                                   \
      __builtin_amdgcn_s_setprio(0);                                                     \
      SM_PHASE(sc0, sc1);                                                                \
    }                                                                                    \
    {                                                                                    \
      f32x16 sc0 = {}, sc1 = {};                                                         \
      __builtin_amdgcn_s_setprio(1);                                                     \
      QK_PHASE(Kc, 1, sc0, sc1);                                                         \
      PV_PHASE(Vcur, 0);                                                                 \
      __builtin_amdgcn_s_setprio(0);                                                     \
      SM_PHASE(sc0, sc1);                                                                \
    }                                                                                    \
  } while (0)

  // prologue: tiles 0,1
  STAGE_T(0);
  STAGE_T(1);
  __syncthreads();

  for (int tp = 0; tp < SS / 64; tp += 2) {
    if (tp + 2 < SS / 64) {
      STAGE_T(tp + 2);
      STAGE_T(tp + 3);
    }
    TILE_BODY(tp);
    TILE_BODY(tp + 1);
    __syncthreads();
  }

  {
    const f16* Vlast = &Vls[(SS / 64 - 1) % 5][0];
    __builtin_amdgcn_s_setprio(1);
    PV_PHASE(Vlast, 2);
    __builtin_amdgcn_s_setprio(0);
  }

  // lane-local normalization: ocsum[f][reg] is the complete row sum for the
  // same q-row oacc[f][*][reg] holds (MFMA K-reduce spans all 64 lanes).
  const int b = bh >> 4, head = bh & 15;
#pragma unroll
  for (int f = 0; f < 2; ++f) {
    f16* aobase = AO + ((size_t)(b * SS + q0 + 64 * w + 32 * f)) * DD + head * 64 + q31;
#pragma unroll
    for (int reg = 0; reg < 16; ++reg) {
      float linv = 1.0f / ocsum[f][reg];
      int q = (reg & 3) + 8 * (reg >> 2) + 4 * h;
#pragma unroll
      for (int vb = 0; vb < 2; ++vb)
        aobase[(size_t)q * DD + 32 * vb] = (f16)(oacc[f][vb][reg] * linv);
    }
  }
#undef STAGE_T
#undef QK_PHASE
#undef PV_PHASE
#undef SM_PHASE
#undef TILE_BODY
}

// ---------------- launch ----------------
extern "C" void kernel_launch(void* const* d_in, const int* in_sizes, int n_in,
                              void* d_out, int out_size, void* d_ws, size_t ws_size,
                              hipStream_t stream) {
  (void)in_sizes; (void)n_in; (void)out_size; (void)ws_size;
  const float* x  = (const float*)d_in[0];
  const float* wq = (const float*)d_in[1];
  const float* bq = (const float*)d_in[2];
  const float* wk = (const float*)d_in[3];
  const float* bk = (const float*)d_in[4];
  const float* wv = (const float*)d_in[5];
  const float* bv = (const float*)d_in[6];
  const float* wo = (const float*)d_in[7];
  const float* bo = (const float*)d_in[8];
  float* out = (float*)d_out;

  char* ws = (char*)d_ws;
  f16* xh  = (f16*)ws; ws += (size_t)MM * DD * 2;
  f16* wqh = (f16*)ws; ws += (size_t)DD * DD * 2;
  f16* wkh = (f16*)ws; ws += (size_t)DD * DD * 2;
  f16* wvh = (f16*)ws; ws += (size_t)DD * DD * 2;
  f16* woh = (f16*)ws; ws += (size_t)DD * DD * 2;
  f16* Qb  = (f16*)ws; ws += (size_t)MM * DD * 2;
  f16* Kb  = (f16*)ws; ws += (size_t)MM * DD * 2;
  f16* Vtb = (f16*)ws; ws += (size_t)MM * DD * 2;
  f16* AOb = (f16*)ws; ws += (size_t)MM * DD * 2;

  cvt_all_kernel<<<MM * DD / 4 / 256 + 4 * (DD * DD / 4 / 256), 256, 0, stream>>>(
      x, wq, wk, wv, wo, xh, wqh, wkh, wvh, woh);

  gemm8_kernel<true><<<768, 512, 0, stream>>>(xh, wqh, wkh, wvh, bq, bk, bv, Qb, Kb, Vtb);

  attn_kernel<<<512, 256, 0, stream>>>(Qb, Kb, Vtb, AOb);

  gemm8_kernel<false><<<256, 512, 0, stream>>>(AOb, woh, nullptr, nullptr, bo, nullptr,
                                               nullptr, out, nullptr, nullptr);
}

// Round 18
// 177.323 us; speedup vs baseline: 1.0433x; 1.0433x over previous
//
#include <hip/hip_runtime.h>
#include <hip/hip_bf16.h>
#include <hip/hip_fp16.h>

typedef _Float16 f16;
typedef f16 f16x8 __attribute__((ext_vector_type(8)));
typedef f16 f16x4 __attribute__((ext_vector_type(4)));
typedef f16 f16x2 __attribute__((ext_vector_type(2)));
typedef float f32x4 __attribute__((ext_vector_type(4)));
typedef float f32x16 __attribute__((ext_vector_type(16)));
typedef unsigned int u32x4 __attribute__((ext_vector_type(4)));
typedef unsigned int u32x2 __attribute__((ext_vector_type(2)));

#define MFMA16(a, b, c) __builtin_amdgcn_mfma_f32_16x16x32_f16(a, b, c, 0, 0, 0)
#define MFMA32(a, b, c) __builtin_amdgcn_mfma_f32_32x32x16_f16(a, b, c, 0, 0, 0)

constexpr int BB = 4, SS = 2048, DD = 1024, HH = 16, HDIM = 64;
constexpr int MM = BB * SS; // 8192
constexpr float QSCALE = 0.125f * 1.44269504088896340736f;

// K/V CHUNK-TILED: 16B chunk (bh, tile, slot, row) at f16 offset
//   (((bh*32 + tile)*8 + slot)*64 + row) * 8
__device__ __forceinline__ void gl_lds16(const void* g, void* l) {
  __builtin_amdgcn_global_load_lds((const __attribute__((address_space(1))) void*)g,
                                   (__attribute__((address_space(3))) void*)l, 16, 0, 0);
}

// ---------------- fp32 -> f16 conversion (x + 4 weights, one launch) ----------------
__global__ __launch_bounds__(256) void cvt_all_kernel(const float* __restrict__ x,
                                                      const float* __restrict__ w0,
                                                      const float* __restrict__ w1,
                                                      const float* __restrict__ w2,
                                                      const float* __restrict__ w3,
                                                      f16* xh, f16* o0, f16* o1,
                                                      f16* o2, f16* o3) {
  int bid = blockIdx.x;
  const float* in; f16* out; int idx;
  if (bid < MM * DD / 4 / 256) {
    in = x; out = xh; idx = bid * 256 + threadIdx.x;
  } else {
    int wb = bid - MM * DD / 4 / 256;
    int which = wb >> 10;
    in = which == 0 ? w0 : which == 1 ? w1 : which == 2 ? w2 : w3;
    out = which == 0 ? o0 : which == 1 ? o1 : which == 2 ? o2 : o3;
    idx = (wb & 1023) * 256 + threadIdx.x;
  }
  f32x4 v = reinterpret_cast<const f32x4*>(in)[idx];
  f16x4 o;
  o[0] = (f16)v[0]; o[1] = (f16)v[1]; o[2] = (f16)v[2]; o[3] = (f16)v[3];
  reinterpret_cast<f16x4*>(out)[idx] = o;
}

// ---------------- 8-wave 256x128 pipelined GEMM (proven) ----------------
template <bool QKV>
__global__ __launch_bounds__(512) void gemm8_kernel(const f16* __restrict__ A,
                                                    const f16* __restrict__ W0,
                                                    const f16* __restrict__ W1,
                                                    const f16* __restrict__ W2,
                                                    const float* __restrict__ b0,
                                                    const float* __restrict__ b1,
                                                    const float* __restrict__ b2,
                                                    void* __restrict__ O0,
                                                    void* __restrict__ O1,
                                                    void* __restrict__ O2) {
  constexpr int NT = 16;
  constexpr int BUF = 256 * 64 + 128 * 64;
  __shared__ __align__(16) f16 smem[3 * BUF];

  const int p = blockIdx.x;
  const int bl = p >> 3;
  const int NS = QKV ? 24 : 8;
  const int nn = bl % NS;
  const int my = (p & 7) + 8 * (bl / NS);
  const int mat = QKV ? (nn >> 3) : 0;
  const int m0 = my * 256;
  const int n0 = (nn & 7) * 128;

  const f16* W = mat == 0 ? W0 : (mat == 1 ? W1 : W2);
  const float* bias = mat == 0 ? b0 : (mat == 1 ? b1 : b2);

  const int tid = threadIdx.x;
  const int w = tid >> 6, lane = tid & 63;
  const int wm = w >> 2, wn = w & 3;
  const int g = lane >> 4, r = lane & 15;

  f32x4 acc[8][2] = {};

#define STAGE_A(I, PB, KT)                                                              \
  do {                                                                                  \
    int cid_ = ((I)*8 + w) * 64 + lane;                                                 \
    int row_ = cid_ >> 3, c_ = cid_ & 7;                                                \
    gl_lds16(A + (size_t)(m0 + row_) * 1024 + (KT) + ((c_ ^ (row_ & 7)) << 3),          \
             smem + (PB) + ((I)*8 + w) * 512);                                          \
  } while (0)
#define STAGE_B(I, PB, KT)                                                              \
  do {                                                                                  \
    int cid_ = ((I)*8 + w) * 64 + lane;                                                 \
    int row_ = cid_ >> 3, c_ = cid_ & 7;                                                \
    gl_lds16(W + (size_t)(n0 + row_) * 1024 + (KT) + ((c_ ^ (row_ & 7)) << 3),          \
             smem + (PB) + 256 * 64 + ((I)*8 + w) * 512);                               \
  } while (0)

#pragma unroll
  for (int i = 0; i < 4; ++i) STAGE_A(i, 0, 0);
#pragma unroll
  for (int i = 0; i < 2; ++i) STAGE_B(i, 0, 0);
#pragma unroll
  for (int i = 0; i < 4; ++i) STAGE_A(i, BUF, 64);
#pragma unroll
  for (int i = 0; i < 2; ++i) STAGE_B(i, BUF, 64);
  __builtin_amdgcn_sched_barrier(0);
  asm volatile("s_waitcnt vmcnt(6)" ::: "memory");
  __builtin_amdgcn_s_barrier();
  __builtin_amdgcn_sched_barrier(0);

  for (int t = 0; t < NT; ++t) {
    const f16* Ab = smem + (t % 3) * BUF;
    const f16* Wb = Ab + 256 * 64;
    const int pb = ((t + 2) % 3) * BUF;
    const int kpf = (t + 2) * 64;
    const bool do_pf = (t + 2) < NT;

    f16x8 wf[2][2];
#pragma unroll
    for (int ks = 0; ks < 2; ++ks)
#pragma unroll
      for (int j = 0; j < 2; ++j) {
        int rowW = wn * 32 + j * 16 + r;
        wf[ks][j] = *reinterpret_cast<const f16x8*>(
            Wb + rowW * 64 + (((ks << 2) | g) ^ (rowW & 7)) * 8);
      }

    if (do_pf) { STAGE_A(0, pb, kpf); STAGE_A(1, pb, kpf); STAGE_B(0, pb, kpf); }
    __builtin_amdgcn_s_setprio(1);
#pragma unroll
    for (int ks = 0; ks < 2; ++ks)
#pragma unroll
      for (int i = 0; i < 4; ++i) {
        int rowA = wm * 128 + i * 16 + r;
        f16x8 af = *reinterpret_cast<const f16x8*>(
            Ab + rowA * 64 + (((ks << 2) | g) ^ (rowA & 7)) * 8);
        acc[i][0] = MFMA16(af, wf[ks][0], acc[i][0]);
        acc[i][1] = MFMA16(af, wf[ks][1], acc[i][1]);
      }
    __builtin_amdgcn_s_setprio(0);

    if (do_pf) { STAGE_A(2, pb, kpf); STAGE_A(3, pb, kpf); STAGE_B(1, pb, kpf); }
    __builtin_amdgcn_s_setprio(1);
#pragma unroll
    for (int ks = 0; ks < 2; ++ks)
#pragma unroll
      for (int i = 0; i < 4; ++i) {
        int rowA = wm * 128 + 64 + i * 16 + r;
        f16x8 af = *reinterpret_cast<const f16x8*>(
            Ab + rowA * 64 + (((ks << 2) | g) ^ (rowA & 7)) * 8);
        acc[4 + i][0] = MFMA16(af, wf[ks][0], acc[4 + i][0]);
        acc[4 + i][1] = MFMA16(af, wf[ks][1], acc[4 + i][1]);
      }
    __builtin_amdgcn_s_setprio(0);

    __builtin_amdgcn_sched_barrier(0);
    if (t < NT - 2) {
      asm volatile("s_waitcnt vmcnt(6)" ::: "memory");
      __builtin_amdgcn_s_barrier();
    } else if (t == NT - 2) {
      asm volatile("s_waitcnt vmcnt(0)" ::: "memory");
      __builtin_amdgcn_s_barrier();
    }
    __builtin_amdgcn_sched_barrier(0);
  }
#undef STAGE_A
#undef STAGE_B

  const int sbase = m0 & 2047, bb = m0 >> 11;
  if constexpr (!QKV) {
    float* Out = reinterpret_cast<float*>(O0);
#pragma unroll
    for (int ii = 0; ii < 8; ++ii) {
      int rowoff = (ii >> 2) * 64 + (ii & 3) * 16;
#pragma unroll
      for (int j = 0; j < 2; ++j)
#pragma unroll
        for (int q = 0; q < 4; ++q) {
          int gm = m0 + wm * 128 + rowoff + g * 4 + q;
          int gn = n0 + wn * 32 + j * 16 + r;
          Out[(size_t)gm * 1024 + gn] = acc[ii][j][q] + bias[gn];
        }
    }
  } else if (mat == 0) {
    f16* Qo = reinterpret_cast<f16*>(O0);
#pragma unroll
    for (int ii = 0; ii < 8; ++ii) {
      int rowoff = (ii >> 2) * 64 + (ii & 3) * 16;
#pragma unroll
      for (int j = 0; j < 2; ++j)
#pragma unroll
        for (int q = 0; q < 4; ++q) {
          int gm = m0 + wm * 128 + rowoff + g * 4 + q;
          int gn = n0 + wn * 32 + j * 16 + r;
          float v = (acc[ii][j][q] + bias[gn]) * QSCALE;
          int b = gm >> 11, s = gm & 2047;
          int hh = gn >> 6, hd = gn & 63;
          Qo[(((size_t)(b * HH + hh)) * SS + s) * HDIM + hd] = (f16)v;
        }
    }
  } else if (mat == 1) {
    f16* Ko = reinterpret_cast<f16*>(O1);
    __syncthreads();
    f16* T = smem;
#pragma unroll
    for (int ii = 0; ii < 8; ++ii) {
      int rowoff = (ii >> 2) * 64 + (ii & 3) * 16;
#pragma unroll
      for (int j = 0; j < 2; ++j)
#pragma unroll
        for (int q = 0; q < 4; ++q) {
          int ml = wm * 128 + rowoff + g * 4 + q;
          int nl = wn * 32 + j * 16 + r;
          T[ml * 136 + nl] = (f16)(acc[ii][j][q] + bias[n0 + nl]);
        }
    }
    __syncthreads();
#pragma unroll
    for (int it = 0; it < 8; ++it) {
      int cid = it * 512 + tid;
      int row_s = cid & 255, ns = cid >> 8;
      u32x4 v = *reinterpret_cast<const u32x4*>(T + row_s * 136 + ns * 8);
      int gn0 = n0 + ns * 8;
      int hh = gn0 >> 6, slot = (gn0 & 63) >> 3;
      int tile = (sbase >> 6) + (row_s >> 6), row = row_s & 63;
      size_t off = ((((size_t)(bb * HH + hh) * 32 + tile) * 8 + slot) * 64 + row) * 8;
      *reinterpret_cast<u32x4*>(Ko + off) = v;
    }
  } else {
    f16* Vo = reinterpret_cast<f16*>(O2);
    __syncthreads();
    f16* T = smem;
#pragma unroll
    for (int ii = 0; ii < 8; ++ii) {
      int rowoff = (ii >> 2) * 64 + (ii & 3) * 16;
#pragma unroll
      for (int j = 0; j < 2; ++j)
#pragma unroll
        for (int q = 0; q < 4; ++q) {
          int ml = wm * 128 + rowoff + g * 4 + q;
          int nl = wn * 32 + j * 16 + r;
          T[nl * 264 + ml] = (f16)(acc[ii][j][q] + bias[n0 + nl]);
        }
    }
    __syncthreads();
#pragma unroll
    for (int it = 0; it < 8; ++it) {
      int cid = it * 512 + tid;
      int hd_l = cid & 127, rest = cid >> 7;
      int sl = rest & 7, tl = rest >> 3;
      u32x4 v = *reinterpret_cast<const u32x4*>(T + hd_l * 264 + tl * 64 + sl * 8);
      int gn = n0 + hd_l, hh = gn >> 6, hd = gn & 63;
      int tile = (sbase >> 6) + tl;
      size_t off = ((((size_t)(bb * HH + hh) * 32 + tile) * 8 + sl) * 64 + hd) * 8;
      *reinterpret_cast<u32x4*>(Vo + off) = v;
    }
  }
}

// ---------------- flash attention (best: 75.9 us): T15 pipeline, 2 tiles/barrier ----------------
// K quad-buffered (reads {t,t+1}, writes {t+2,t+3} mod 4 — disjoint),
// V penta-buffered (reads {t-1,t,t+1}, writes {t+2,t+3} mod 5 — disjoint).
__global__ __launch_bounds__(256, 2) void attn_kernel(const f16* __restrict__ Q,
                                                      const f16* __restrict__ K,
                                                      const f16* __restrict__ Vt,
                                                      f16* __restrict__ AO) {
  __shared__ __align__(16) f16 Kls[4][8 * 512];
  __shared__ __align__(16) f16 Vls[5][8 * 512];
  __shared__ __align__(16) float Lw[4][64];

  const int p = blockIdx.x;
  const int qx = (p >> 3) & 7;
  const int bh = (p & 7) | ((p >> 6) << 3);
  const int q0 = qx * 256;

  const int tid = threadIdx.x;
  const int w = tid >> 6, lane = tid & 63;
  const int q31 = lane & 31;
  const int h = lane >> 5;
  const f16* Kg = K + (size_t)bh * (SS * HDIM);
  const f16* Vg = Vt + (size_t)bh * (SS * HDIM);
  const int s0 = 2 * w;
  const int rofs = h * 512 + q31 * 8;

  const f16* Qg = Q + ((size_t)bh * SS + q0 + w * 64 + q31) * HDIM + 8 * h;
  f16x8 qf[2][4];
#pragma unroll
  for (int f = 0; f < 2; ++f)
#pragma unroll
    for (int m = 0; m < 4; ++m)
      qf[f][m] = *reinterpret_cast<const f16x8*>(Qg + f * 32 * HDIM + 16 * m);

  f32x16 oacc[2][2] = {};
  float lsum0 = 0.f, lsum1 = 0.f;
  unsigned pkP0[8], pkP1[8];

#define STAGE_T(T1)                                                                      \
  do {                                                                                   \
    f16* kdst = &Kls[(T1) & 3][0];                                                       \
    f16* vdst = &Vls[(T1) % 5][0];                                                       \
    _Pragma("unroll") for (int i = 0; i < 2; ++i) {                                      \
      int s_idx = s0 + i;                                                                \
      gl_lds16(Kg + (size_t)((T1)*512 + s_idx * 64 + lane) * 8, kdst + s_idx * 512);     \
      gl_lds16(Vg + (size_t)((T1)*512 + s_idx * 64 + lane) * 8, vdst + s_idx * 512);     \
    }                                                                                    \
  } while (0)

#define QK_PHASE(KC, KB, SC0, SC1)                                                   \
  do {                                                                               \
    _Pragma("unroll") for (int m = 0; m < 4; ++m) {                                  \
      f16x8 kf = *reinterpret_cast<const f16x8*>((KC) + m * 1024 + (KB)*256 + rofs); \
      SC0 = MFMA32(kf, qf[0][m], SC0);                                               \
      SC1 = MFMA32(kf, qf[1][m], SC1);                                               \
    }                                                                                \
  } while (0)

#define PV_PHASE(VPTR, JB)                                                               \
  do {                                                                                   \
    _Pragma("unroll") for (int jl = 0; jl < 2; ++jl) {                                   \
      auto a0 = __builtin_amdgcn_permlane32_swap(pkP0[4 * jl + 0], pkP0[4 * jl + 2],     \
                                                 false, false);                          \
      auto a1 = __builtin_amdgcn_permlane32_swap(pkP0[4 * jl + 1], pkP0[4 * jl + 3],     \
                                                 false, false);                          \
      u32x4 fa = {(unsigned)a0[0], (unsigned)a1[0], (unsigned)a0[1], (unsigned)a1[1]};   \
      f16x8 pa0 = __builtin_bit_cast(f16x8, fa);                                         \
      auto b0 = __builtin_amdgcn_permlane32_swap(pkP1[4 * jl + 0], pkP1[4 * jl + 2],     \
                                                 false, false);                          \
      auto b1 = __builtin_amdgcn_permlane32_swap(pkP1[4 * jl + 1], pkP1[4 * jl + 3],     \
                                                 false, false);                          \
      u32x4 fb = {(unsigned)b0[0], (unsigned)b1[0], (unsigned)b0[1], (unsigned)b1[1]};   \
      f16x8 pa1 = __builtin_bit_cast(f16x8, fb);                                         \
      const int j = (JB) + jl;                                                           \
      _Pragma("unroll") for (int vb = 0; vb < 2; ++vb) {                                 \
        f16x8 vbf = *reinterpret_cast<const f16x8*>((VPTR) + j * 1024 + vb * 256 + rofs);\
        oacc[0][vb] = MFMA32(pa0, vbf, oacc[0][vb]);                                     \
        oacc[1][vb] = MFMA32(pa1, vbf, oacc[1][vb]);                                     \
      }                                                                                  \
    }                                                                                    \
  } while (0)

#define SM_PHASE(SC0, SC1)                                                               \
  do {                                                                                   \
    _Pragma("unroll") for (int rp = 0; rp < 4; ++rp)                                     \
        _Pragma("unroll") for (int pp = 0; pp < 2; ++pp) {                               \
      float a0 = __builtin_amdgcn_exp2f((SC0)[4 * rp + 2 * pp]);                         \
      float a1 = __builtin_amdgcn_exp2f((SC0)[4 * rp + 2 * pp + 1]);                     \
      pkP0[2 * rp + pp] = __builtin_bit_cast(unsigned, __builtin_amdgcn_cvt_pkrtz(a0, a1));\
      float b0 = __builtin_amdgcn_exp2f((SC1)[4 * rp + 2 * pp]);                         \
      float b1 = __builtin_amdgcn_exp2f((SC1)[4 * rp + 2 * pp + 1]);                     \
      pkP1[2 * rp + pp] = __builtin_bit_cast(unsigned, __builtin_amdgcn_cvt_pkrtz(b0, b1));\
    }                                                                                    \
    {                                                                                    \
      f16x2 u01 = __builtin_bit_cast(f16x2, pkP0[0]) + __builtin_bit_cast(f16x2, pkP0[1]);\
      f16x2 u23 = __builtin_bit_cast(f16x2, pkP0[2]) + __builtin_bit_cast(f16x2, pkP0[3]);\
      f16x2 u45 = __builtin_bit_cast(f16x2, pkP0[4]) + __builtin_bit_cast(f16x2, pkP0[5]);\
      f16x2 u67 = __builtin_bit_cast(f16x2, pkP0[6]) + __builtin_bit_cast(f16x2, pkP0[7]);\
      f16x2 ut = (u01 + u23) + (u45 + u67);                                              \
      lsum0 += (float)ut[0] + (float)ut[1];                                              \
    }                                                                                    \
    {                                                                                    \
      f16x2 u01 = __builtin_bit_cast(f16x2, pkP1[0]) + __builtin_bit_cast(f16x2, pkP1[1]);\
      f16x2 u23 = __builtin_bit_cast(f16x2, pkP1[2]) + __builtin_bit_cast(f16x2, pkP1[3]);\
      f16x2 u45 = __builtin_bit_cast(f16x2, pkP1[4]) + __builtin_bit_cast(f16x2, pkP1[5]);\
      f16x2 u67 = __builtin_bit_cast(f16x2, pkP1[6]) + __builtin_bit_cast(f16x2, pkP1[7]);\
      f16x2 ut = (u01 + u23) + (u45 + u67);                                              \
      lsum1 += (float)ut[0] + (float)ut[1];                                              \
    }                                                                                    \
  } while (0)

// one 64-k tile: phases A and B (QK || PVprev || SM), T15 cross-tile lag
#define TILE_BODY(T)                                                                     \
  do {                                                                                   \
    const f16* Kc = &Kls[(T) & 3][0];                                                    \
    const f16* Vcur = &Vls[(T) % 5][0];                                                  \
    const f16* Vprev = &Vls[((T) + 4) % 5][0];                                           \
    {                                                                                    \
      f32x16 sc0 = {}, sc1 = {};                                                         \
      __builtin_amdgcn_s_setprio(1);                                                     \
      QK_PHASE(Kc, 0, sc0, sc1);                                                         \
      if ((T) > 0) PV_PHASE(Vprev, 2);                                                   \
      __builtin_amdgcn_s_setprio(0);                                                     \
      SM_PHASE(sc0, sc1);                                                                \
    }                                                                                    \
    {                                                                                    \
      f32x16 sc0 = {}, sc1 = {};                                                         \
      __builtin_amdgcn_s_setprio(1);                                                     \
      QK_PHASE(Kc, 1, sc0, sc1);                                                         \
      PV_PHASE(Vcur, 0);                                                                 \
      __builtin_amdgcn_s_setprio(0);                                                     \
      SM_PHASE(sc0, sc1);                                                                \
    }                                                                                    \
  } while (0)

  // prologue: tiles 0,1
  STAGE_T(0);
  STAGE_T(1);
  __syncthreads();

  for (int tp = 0; tp < SS / 64; tp += 2) {
    if (tp + 2 < SS / 64) {
      STAGE_T(tp + 2);
      STAGE_T(tp + 3);
    }
    TILE_BODY(tp);
    TILE_BODY(tp + 1);
    __syncthreads();
  }

  {
    const f16* Vlast = &Vls[(SS / 64 - 1) % 5][0];
    __builtin_amdgcn_s_setprio(1);
    PV_PHASE(Vlast, 2);
    __builtin_amdgcn_s_setprio(0);
  }

  lsum0 += __shfl_xor(lsum0, 32, 64);
  lsum1 += __shfl_xor(lsum1, 32, 64);
  if (h == 0) {
    Lw[w][q31] = 1.0f / lsum0;
    Lw[w][32 + q31] = 1.0f / lsum1;
  }

  const int b = bh >> 4, head = bh & 15;
#pragma unroll
  for (int f = 0; f < 2; ++f) {
    f32x4 li[4];
#pragma unroll
    for (int rq = 0; rq < 4; ++rq)
      li[rq] = *reinterpret_cast<const f32x4*>(&Lw[w][32 * f + 8 * rq + 4 * h]);
    f16* aobase = AO + ((size_t)(b * SS + q0 + 64 * w + 32 * f)) * DD + head * 64 + q31;
#pragma unroll
    for (int vb = 0; vb < 2; ++vb)
#pragma unroll
      for (int reg = 0; reg < 16; ++reg) {
        int q = (reg & 3) + 8 * (reg >> 2) + 4 * h;
        aobase[(size_t)q * DD + 32 * vb] = (f16)(oacc[f][vb][reg] * li[reg >> 2][reg & 3]);
      }
  }
#undef STAGE_T
#undef QK_PHASE
#undef PV_PHASE
#undef SM_PHASE
#undef TILE_BODY
}

// ---------------- launch ----------------
extern "C" void kernel_launch(void* const* d_in, const int* in_sizes, int n_in,
                              void* d_out, int out_size, void* d_ws, size_t ws_size,
                              hipStream_t stream) {
  (void)in_sizes; (void)n_in; (void)out_size; (void)ws_size;
  const float* x  = (const float*)d_in[0];
  const float* wq = (const float*)d_in[1];
  const float* bq = (const float*)d_in[2];
  const float* wk = (const float*)d_in[3];
  const float* bk = (const float*)d_in[4];
  const float* wv = (const float*)d_in[5];
  const float* bv = (const float*)d_in[6];
  const float* wo = (const float*)d_in[7];
  const float* bo = (const float*)d_in[8];
  float* out = (float*)d_out;

  char* ws = (char*)d_ws;
  f16* xh  = (f16*)ws; ws += (size_t)MM * DD * 2;
  f16* wqh = (f16*)ws; ws += (size_t)DD * DD * 2;
  f16* wkh = (f16*)ws; ws += (size_t)DD * DD * 2;
  f16* wvh = (f16*)ws; ws += (size_t)DD * DD * 2;
  f16* woh = (f16*)ws; ws += (size_t)DD * DD * 2;
  f16* Qb  = (f16*)ws; ws += (size_t)MM * DD * 2;
  f16* Kb  = (f16*)ws; ws += (size_t)MM * DD * 2;
  f16* Vtb = (f16*)ws; ws += (size_t)MM * DD * 2;
  f16* AOb = (f16*)ws; ws += (size_t)MM * DD * 2;

  cvt_all_kernel<<<MM * DD / 4 / 256 + 4 * (DD * DD / 4 / 256), 256, 0, stream>>>(
      x, wq, wk, wv, wo, xh, wqh, wkh, wvh, woh);

  gemm8_kernel<true><<<768, 512, 0, stream>>>(xh, wqh, wkh, wvh, bq, bk, bv, Qb, Kb, Vtb);

  attn_kernel<<<512, 256, 0, stream>>>(Qb, Kb, Vtb, AOb);

  gemm8_kernel<false><<<256, 512, 0, stream>>>(AOb, woh, nullptr, nullptr, bo, nullptr,
                                               nullptr, out, nullptr, nullptr);
}